// Round 8
// baseline (1018.573 us; speedup 1.0000x reference)
//
#include <hip/hip_runtime.h>

// GCN 3-layer forward, fp32 — Round 8: edge-parallel LDS-atomic aggregation.
//   agg(X@W) == agg(X)@W  =>  per layer: gather-sum -> in-block GEMM -> bias/act.
//   Block owns 16 dst nodes => their CSR lists are ONE contiguous col range.
//   All 4 waves consume it edge-parallel: 64 lanes = 64 features of the source
//   row (256B coalesced), accumulated into a 16-row LDS tile via ds_add_f32.
//   col is PACKED: bits 0..16 = src, bits 28..31 = dst&15 (local row) -> no
//   per-edge rowptr/rank lookup in the hot loop.
//   dinv[i] = rsqrt(1+indeg(i)); intermediates emit y*dinv (pre-scaled);
//   layer 0 multiplies by dinv[src] on the fly (PRE).

#define FEAT 64
#define SCAN_B 1024
#define STILE 68   // LDS tile stride: 64+4 -> 2-way bank aliasing only (free)

typedef int v4i __attribute__((ext_vector_type(4)));

// ---------- CSR build ----------
__global__ void deg_rank_kernel(const int* __restrict__ dst, int* __restrict__ cnt,
                                int* __restrict__ rank, int E4) {
    int i = blockIdx.x * blockDim.x + threadIdx.x;
    if (i < E4) {
        v4i d = __builtin_nontemporal_load(((const v4i*)dst) + i);
        v4i r;
        r[0] = atomicAdd(&cnt[d[0]], 1);
        r[1] = atomicAdd(&cnt[d[1]], 1);
        r[2] = atomicAdd(&cnt[d[2]], 1);
        r[3] = atomicAdd(&cnt[d[3]], 1);
        __builtin_nontemporal_store(r, ((v4i*)rank) + i);
    }
}

// Pass 1: per-block exclusive scan of 1024-chunk -> rowptr (chunk-local), bsum.
// Also emits dinv[i] = rsqrt(1+cnt[i]).
__global__ __launch_bounds__(SCAN_B) void scan_partial_kernel(
    const int* __restrict__ cnt, int* __restrict__ rowptr,
    int* __restrict__ bsum, float* __restrict__ dinv, int n) {
    __shared__ int wsum[SCAN_B / 64 + 1];
    const int tid  = threadIdx.x;
    const int lane = tid & 63;
    const int wid  = tid >> 6;
    const int i = blockIdx.x * SCAN_B + tid;

    int v = (i < n) ? cnt[i] : 0;
    if (i < n) dinv[i] = rsqrtf((float)(1 + v));
    int incl = v;
#pragma unroll
    for (int off = 1; off < 64; off <<= 1) {
        int t = __shfl_up(incl, off, 64);
        if (lane >= off) incl += t;
    }
    if (lane == 63) wsum[wid] = incl;
    __syncthreads();
    if (tid == 0) {
        int run = 0;
#pragma unroll
        for (int w = 0; w < SCAN_B / 64; ++w) { int t = wsum[w]; wsum[w] = run; run += t; }
        wsum[SCAN_B / 64] = run;
        bsum[blockIdx.x] = run;
    }
    __syncthreads();
    if (i < n) rowptr[i] = incl - v + wsum[wid];
}

// Pass 2: exclusive scan of block sums, single block, nb <= 1024.
__global__ __launch_bounds__(SCAN_B) void scan_sums_kernel(int* __restrict__ bsum, int nb) {
    __shared__ int wsum[SCAN_B / 64 + 1];
    const int tid  = threadIdx.x;
    const int lane = tid & 63;
    const int wid  = tid >> 6;
    int v = (tid < nb) ? bsum[tid] : 0;
    int incl = v;
#pragma unroll
    for (int off = 1; off < 64; off <<= 1) {
        int t = __shfl_up(incl, off, 64);
        if (lane >= off) incl += t;
    }
    if (lane == 63) wsum[wid] = incl;
    __syncthreads();
    if (tid == 0) {
        int run = 0;
#pragma unroll
        for (int w = 0; w < SCAN_B / 64; ++w) { int t = wsum[w]; wsum[w] = run; run += t; }
        wsum[SCAN_B / 64] = run;
    }
    __syncthreads();
    if (tid < nb) bsum[tid] = incl - v + wsum[wid];
    if (tid == 0) bsum[nb] = wsum[SCAN_B / 64];
}

// Pass 3: add block offsets; write rowptr[n].
__global__ __launch_bounds__(SCAN_B) void scan_add_kernel(
    int* __restrict__ rowptr, const int* __restrict__ bsum, int n, int nb) {
    const int i = blockIdx.x * SCAN_B + (int)threadIdx.x;
    if (i < n) rowptr[i] += bsum[blockIdx.x];
    if (i == 0) rowptr[n] = bsum[nb];
}

// Atomic-free CSR fill. Packs local dst row (dst&15) into bits 28..31.
__global__ void fill_kernel(const int* __restrict__ src, const int* __restrict__ dst,
                            const int* __restrict__ rank, const int* __restrict__ rowptr,
                            int* __restrict__ col, int E4) {
    int i = blockIdx.x * blockDim.x + threadIdx.x;
    if (i < E4) {
        v4i s = __builtin_nontemporal_load(((const v4i*)src) + i);
        v4i d = __builtin_nontemporal_load(((const v4i*)dst) + i);
        v4i r = __builtin_nontemporal_load(((const v4i*)rank) + i);
        col[rowptr[d[0]] + r[0]] = s[0] | ((d[0] & 15) << 28);
        col[rowptr[d[1]] + r[1]] = s[1] | ((d[1] & 15) << 28);
        col[rowptr[d[2]] + r[2]] = s[2] | ((d[2] & 15) << 28);
        col[rowptr[d[3]] + r[3]] = s[3] | ((d[3] & 15) << 28);
    }
}

// ---------- fused layer: edge-parallel gather -> LDS tile -> GEMM -> bias/act
// 16 nodes/block (N % 16 == 0). Waves process the block's contiguous packed-col
// range edge-parallel: per edge, 64 lanes load the source row (1 float/lane,
// 256B coalesced) and ds_add into s_tile[localRow][lane].
template<int INTER, int PRE>
__global__ __launch_bounds__(256) void layer_kernel(
    const int* __restrict__ rowptr, const int* __restrict__ colp,
    const float* __restrict__ dinv, const float* __restrict__ Xs,
    const float* __restrict__ W, const float* __restrict__ bias,
    float* __restrict__ out, int n) {
    __shared__ float w_lds[FEAT * FEAT];   // [k][c]
    __shared__ float s_tile[16 * STILE];   // [r][feat] accumulator, padded

    const int t = threadIdx.x;
#pragma unroll
    for (int i = 0; i < 4; ++i) {
        int idx = (i * 256 + t) * 4;
        *(float4*)&w_lds[idx] = *(const float4*)&W[idx];
    }

    const int r  = t >> 4;       // local node 0..15
    const int c4 = t & 15;       // float4 feature group
    const int g0 = blockIdx.x * 16;
    const int g  = g0 + r;
    const int f  = c4 * 4;

    // self-loop init of the accumulator tile
    const float dg = dinv[g];
    float4 a = *(const float4*)&Xs[(size_t)g * FEAT + f];
    if (PRE) { a.x *= dg; a.y *= dg; a.z *= dg; a.w *= dg; }
    *(float4*)&s_tile[r * STILE + f] = a;
    __syncthreads();   // tile + W visible

    // edge-parallel aggregation over the block's contiguous col range
    const int ebase = rowptr[g0];
    const int nE    = rowptr[g0 + 16] - ebase;
    const int wv    = t >> 6;     // wave 0..3
    const int lane  = t & 63;     // feature index

    for (int q = wv; q * 4 < nE; q += 4) {
        const int p0 = ebase + q * 4;
        const int m  = nE - q * 4;
#pragma unroll
        for (int j = 0; j < 4; ++j) {
            if (j < m) {
                const int word = colp[p0 + j];
                const int rr = ((unsigned)word) >> 28;
                const int s  = word & 0x0FFFFFFF;
                float v = Xs[(size_t)s * FEAT + lane];
                if (PRE) v *= dinv[s];
                atomicAdd(&s_tile[rr * STILE + lane], v);   // ds_add_f32
            }
        }
    }
    __syncthreads();

    // in-block GEMM: T[r][f..f+3] = sum_k S[r][k] * W[k][f..f+3]
    float4 acc = make_float4(0.f, 0.f, 0.f, 0.f);
#pragma unroll
    for (int k = 0; k < FEAT; ++k) {
        const float sv = s_tile[r * STILE + k];              // 16-way broadcast
        const float4 wvv = *(const float4*)&w_lds[k * FEAT + f];  // 4-way broadcast
        acc.x += sv * wvv.x; acc.y += sv * wvv.y;
        acc.z += sv * wvv.z; acc.w += sv * wvv.w;
    }

    const float4 bv = *(const float4*)&bias[f];
    float4 o = make_float4(acc.x * dg + bv.x, acc.y * dg + bv.y,
                           acc.z * dg + bv.z, acc.w * dg + bv.w);
    if (INTER) {   // ReLU, then pre-scale for next layer's gather
        o.x = fmaxf(o.x, 0.f) * dg; o.y = fmaxf(o.y, 0.f) * dg;
        o.z = fmaxf(o.z, 0.f) * dg; o.w = fmaxf(o.w, 0.f) * dg;
    }
    *(float4*)&out[(size_t)g * FEAT + f] = o;
}

extern "C" void kernel_launch(void* const* d_in, const int* in_sizes, int n_in,
                              void* d_out, int out_size, void* d_ws, size_t ws_size,
                              hipStream_t stream) {
    const float* x  = (const float*)d_in[0];
    const int*   ei = (const int*)d_in[1];
    const float* W0 = (const float*)d_in[2];
    const float* b0 = (const float*)d_in[3];
    const float* W1 = (const float*)d_in[4];
    const float* b1 = (const float*)d_in[5];
    const float* W2 = (const float*)d_in[6];
    const float* b2 = (const float*)d_in[7];
    float* out = (float*)d_out;

    const int N = in_sizes[0] / FEAT;   // 50000 (divisible by 16)
    const int E = in_sizes[1] / 2;      // 800000 (divisible by 4)
    const int* src = ei;
    const int* dst = ei + E;

    const int nbScan = (N + SCAN_B - 1) / SCAN_B;   // 49

    // workspace layout
    char* w = (char*)d_ws;
    int*   cnt    = (int*)w;                 w += sizeof(int) * (size_t)N;
    int*   rowptr = (int*)w;                 w += sizeof(int) * (size_t)(N + 1);
    int*   bsum   = (int*)w;                 w += sizeof(int) * (size_t)(nbScan + 1);
    int*   col    = (int*)w;                 w += sizeof(int) * (size_t)E;
    float* dinv   = (float*)w;               w += sizeof(float) * (size_t)N;
    float* B1     = (float*)w;               w += sizeof(float) * (size_t)N * FEAT;
    float* B2     = (float*)w;               w += sizeof(float) * (size_t)N * FEAT;
    int*   rank   = (int*)B2;   // alias: rank dead before layer0 writes B2

    const int tB = 256;
    const int E4  = E / 4;
    const int gE4 = (E4 + tB - 1) / tB;
    const int g16 = (N + 15) / 16;

    // CSR build (shared by all 3 layers)
    hipMemsetAsync(cnt, 0, sizeof(int) * (size_t)N, stream);
    deg_rank_kernel<<<gE4, tB, 0, stream>>>(dst, cnt, rank, E4);
    scan_partial_kernel<<<nbScan, SCAN_B, 0, stream>>>(cnt, rowptr, bsum, dinv, N);
    scan_sums_kernel<<<1, SCAN_B, 0, stream>>>(bsum, nbScan);
    scan_add_kernel<<<nbScan, SCAN_B, 0, stream>>>(rowptr, bsum, N, nbScan);
    fill_kernel<<<gE4, tB, 0, stream>>>(src, dst, rank, rowptr, col, E4);

    // fused layers (layer 0 prescales its gather on the fly)
    layer_kernel<1, 1><<<g16, tB, 0, stream>>>(rowptr, col, dinv, x,  W0, b0, B2, N);
    layer_kernel<1, 0><<<g16, tB, 0, stream>>>(rowptr, col, dinv, B2, W1, b1, B1, N);
    layer_kernel<0, 0><<<g16, tB, 0, stream>>>(rowptr, col, dinv, B1, W2, b2, out, N);
}

// Round 9
// 267.811 us; speedup vs baseline: 3.8033x; 3.8033x over previous
//
#include <hip/hip_runtime.h>

// GCN 3-layer forward, fp32 — Round 9: revert to R7 node-parallel structure
// (R8 edge-parallel+LDS-atomics regressed 4x), gather unrolled 8-wide with 4
// independent accumulators for deeper MLP.
//   agg(X@W) == agg(X)@W  =>  per layer: gather-sum -> in-block GEMM -> bias/act.
//   dinv[i] = rsqrt(1+indeg(i)); intermediates emit y*dinv (pre-scaled);
//   layer 0 multiplies by dinv[src] on the fly (PRE).

#define FEAT 64
#define SCAN_B 1024
#define STILE 68   // s_tile stride: breaks 4-way LDS bank conflict on k-loop

typedef int v4i __attribute__((ext_vector_type(4)));

// ---------- CSR build ----------
// degree count; atomic return value = within-row rank of edge e. Only dst needed.
__global__ void deg_rank_kernel(const int* __restrict__ dst, int* __restrict__ cnt,
                                int* __restrict__ rank, int E4) {
    int i = blockIdx.x * blockDim.x + threadIdx.x;
    if (i < E4) {
        v4i d = __builtin_nontemporal_load(((const v4i*)dst) + i);
        v4i r;
        r[0] = atomicAdd(&cnt[d[0]], 1);
        r[1] = atomicAdd(&cnt[d[1]], 1);
        r[2] = atomicAdd(&cnt[d[2]], 1);
        r[3] = atomicAdd(&cnt[d[3]], 1);
        __builtin_nontemporal_store(r, ((v4i*)rank) + i);
    }
}

// Pass 1: per-block exclusive scan of 1024-chunk -> rowptr (chunk-local), bsum.
// Also emits dinv[i] = rsqrt(1+cnt[i]).
__global__ __launch_bounds__(SCAN_B) void scan_partial_kernel(
    const int* __restrict__ cnt, int* __restrict__ rowptr,
    int* __restrict__ bsum, float* __restrict__ dinv, int n) {
    __shared__ int wsum[SCAN_B / 64 + 1];
    const int tid  = threadIdx.x;
    const int lane = tid & 63;
    const int wid  = tid >> 6;
    const int i = blockIdx.x * SCAN_B + tid;

    int v = (i < n) ? cnt[i] : 0;
    if (i < n) dinv[i] = rsqrtf((float)(1 + v));
    int incl = v;
#pragma unroll
    for (int off = 1; off < 64; off <<= 1) {
        int t = __shfl_up(incl, off, 64);
        if (lane >= off) incl += t;
    }
    if (lane == 63) wsum[wid] = incl;
    __syncthreads();
    if (tid == 0) {
        int run = 0;
#pragma unroll
        for (int w = 0; w < SCAN_B / 64; ++w) { int t = wsum[w]; wsum[w] = run; run += t; }
        wsum[SCAN_B / 64] = run;
        bsum[blockIdx.x] = run;
    }
    __syncthreads();
    if (i < n) rowptr[i] = incl - v + wsum[wid];
}

// Pass 2: exclusive scan of block sums, single block, nb <= 1024.
__global__ __launch_bounds__(SCAN_B) void scan_sums_kernel(int* __restrict__ bsum, int nb) {
    __shared__ int wsum[SCAN_B / 64 + 1];
    const int tid  = threadIdx.x;
    const int lane = tid & 63;
    const int wid  = tid >> 6;
    int v = (tid < nb) ? bsum[tid] : 0;
    int incl = v;
#pragma unroll
    for (int off = 1; off < 64; off <<= 1) {
        int t = __shfl_up(incl, off, 64);
        if (lane >= off) incl += t;
    }
    if (lane == 63) wsum[wid] = incl;
    __syncthreads();
    if (tid == 0) {
        int run = 0;
#pragma unroll
        for (int w = 0; w < SCAN_B / 64; ++w) { int t = wsum[w]; wsum[w] = run; run += t; }
        wsum[SCAN_B / 64] = run;
    }
    __syncthreads();
    if (tid < nb) bsum[tid] = incl - v + wsum[wid];
    if (tid == 0) bsum[nb] = wsum[SCAN_B / 64];
}

// Pass 3: add block offsets; write rowptr[n].
__global__ __launch_bounds__(SCAN_B) void scan_add_kernel(
    int* __restrict__ rowptr, const int* __restrict__ bsum, int n, int nb) {
    const int i = blockIdx.x * SCAN_B + (int)threadIdx.x;
    if (i < n) rowptr[i] += bsum[blockIdx.x];
    if (i == 0) rowptr[n] = bsum[nb];
}

// Atomic-free CSR fill.
__global__ void fill_kernel(const int* __restrict__ src, const int* __restrict__ dst,
                            const int* __restrict__ rank, const int* __restrict__ rowptr,
                            int* __restrict__ col, int E4) {
    int i = blockIdx.x * blockDim.x + threadIdx.x;
    if (i < E4) {
        v4i s = __builtin_nontemporal_load(((const v4i*)src) + i);
        v4i d = __builtin_nontemporal_load(((const v4i*)dst) + i);
        v4i r = __builtin_nontemporal_load(((const v4i*)rank) + i);
        col[rowptr[d[0]] + r[0]] = s[0];
        col[rowptr[d[1]] + r[1]] = s[1];
        col[rowptr[d[2]] + r[2]] = s[2];
        col[rowptr[d[3]] + r[3]] = s[3];
    }
}

// ---------- fused layer: gather-sum -> LDS -> GEMM -> bias/act ----------
// 16 nodes per block, 16 lanes per node (float4/lane). 8-wide unrolled gather,
// 4 independent accumulators -> 8 float4 loads in flight per wave.
// Aggregated rows are wave-private in LDS; only barrier is after the W load.
template<int INTER, int PRE>
__global__ __launch_bounds__(256) void layer_kernel(
    const int* __restrict__ rowptr, const int* __restrict__ col,
    const float* __restrict__ dinv, const float* __restrict__ Xs,
    const float* __restrict__ W, const float* __restrict__ bias,
    float* __restrict__ out, int n) {
    __shared__ float w_lds[FEAT * FEAT];   // [k][c]
    __shared__ float s_tile[16 * STILE];   // [r][k], padded

    const int t = threadIdx.x;
#pragma unroll
    for (int i = 0; i < 4; ++i) {
        int idx = (i * 256 + t) * 4;
        *(float4*)&w_lds[idx] = *(const float4*)&W[idx];
    }
    __syncthreads();   // W visible; nothing else needs a barrier below

    const int r  = t >> 4;       // local node 0..15
    const int c4 = t & 15;       // float4 feature group
    const int g  = blockIdx.x * 16 + r;
    if (g >= n) return;
    const int f = c4 * 4;
    const float* __restrict__ Hf = Xs + f;

    const float dg = dinv[g];

    // self-loop term
    float4 a0 = *(const float4*)&Hf[(size_t)g * FEAT];
    if (PRE) { a0.x *= dg; a0.y *= dg; a0.z *= dg; a0.w *= dg; }
    float4 a1 = make_float4(0.f, 0.f, 0.f, 0.f);
    float4 a2 = make_float4(0.f, 0.f, 0.f, 0.f);
    float4 a3 = make_float4(0.f, 0.f, 0.f, 0.f);

    int p = rowptr[g];
    const int end = rowptr[g + 1];

    for (; p + 8 <= end; p += 8) {
        const int s0 = col[p + 0];
        const int s1 = col[p + 1];
        const int s2 = col[p + 2];
        const int s3 = col[p + 3];
        const int s4 = col[p + 4];
        const int s5 = col[p + 5];
        const int s6 = col[p + 6];
        const int s7 = col[p + 7];
        float4 h0 = *(const float4*)&Hf[(size_t)s0 * FEAT];
        float4 h1 = *(const float4*)&Hf[(size_t)s1 * FEAT];
        float4 h2 = *(const float4*)&Hf[(size_t)s2 * FEAT];
        float4 h3 = *(const float4*)&Hf[(size_t)s3 * FEAT];
        float4 h4 = *(const float4*)&Hf[(size_t)s4 * FEAT];
        float4 h5 = *(const float4*)&Hf[(size_t)s5 * FEAT];
        float4 h6 = *(const float4*)&Hf[(size_t)s6 * FEAT];
        float4 h7 = *(const float4*)&Hf[(size_t)s7 * FEAT];
        if (PRE) {
            const float d0 = dinv[s0], d1 = dinv[s1], d2 = dinv[s2], d3 = dinv[s3];
            const float d4 = dinv[s4], d5 = dinv[s5], d6 = dinv[s6], d7 = dinv[s7];
            h0.x *= d0; h0.y *= d0; h0.z *= d0; h0.w *= d0;
            h1.x *= d1; h1.y *= d1; h1.z *= d1; h1.w *= d1;
            h2.x *= d2; h2.y *= d2; h2.z *= d2; h2.w *= d2;
            h3.x *= d3; h3.y *= d3; h3.z *= d3; h3.w *= d3;
            h4.x *= d4; h4.y *= d4; h4.z *= d4; h4.w *= d4;
            h5.x *= d5; h5.y *= d5; h5.z *= d5; h5.w *= d5;
            h6.x *= d6; h6.y *= d6; h6.z *= d6; h6.w *= d6;
            h7.x *= d7; h7.y *= d7; h7.z *= d7; h7.w *= d7;
        }
        a0.x += h0.x; a0.y += h0.y; a0.z += h0.z; a0.w += h0.w;
        a1.x += h1.x; a1.y += h1.y; a1.z += h1.z; a1.w += h1.w;
        a2.x += h2.x; a2.y += h2.y; a2.z += h2.z; a2.w += h2.w;
        a3.x += h3.x; a3.y += h3.y; a3.z += h3.z; a3.w += h3.w;
        a0.x += h4.x; a0.y += h4.y; a0.z += h4.z; a0.w += h4.w;
        a1.x += h5.x; a1.y += h5.y; a1.z += h5.z; a1.w += h5.w;
        a2.x += h6.x; a2.y += h6.y; a2.z += h6.z; a2.w += h6.w;
        a3.x += h7.x; a3.y += h7.y; a3.z += h7.z; a3.w += h7.w;
    }
    for (; p < end; ++p) {
        const int s = col[p];
        float4 h = *(const float4*)&Hf[(size_t)s * FEAT];
        if (PRE) {
            const float d = dinv[s];
            h.x *= d; h.y *= d; h.z *= d; h.w *= d;
        }
        a0.x += h.x; a0.y += h.y; a0.z += h.z; a0.w += h.w;
    }
    float4 S = make_float4((a0.x + a1.x) + (a2.x + a3.x),
                           (a0.y + a1.y) + (a2.y + a3.y),
                           (a0.z + a1.z) + (a2.z + a3.z),
                           (a0.w + a1.w) + (a2.w + a3.w));
    *(float4*)&s_tile[r * STILE + f] = S;
    // no __syncthreads: wave w reads only rows 4w..4w+3, which it wrote

    // in-block GEMM: T[r][f..f+3] = sum_k S[r][k] * W[k][f..f+3]
    float4 acc = make_float4(0.f, 0.f, 0.f, 0.f);
#pragma unroll
    for (int k = 0; k < FEAT; ++k) {
        const float sv = s_tile[r * STILE + k];
        const float4 wv = *(const float4*)&w_lds[k * FEAT + f];
        acc.x += sv * wv.x; acc.y += sv * wv.y;
        acc.z += sv * wv.z; acc.w += sv * wv.w;
    }

    const float4 bv = *(const float4*)&bias[f];
    float4 o = make_float4(acc.x * dg + bv.x, acc.y * dg + bv.y,
                           acc.z * dg + bv.z, acc.w * dg + bv.w);
    if (INTER) {   // ReLU, then pre-scale for next layer's gather
        o.x = fmaxf(o.x, 0.f) * dg; o.y = fmaxf(o.y, 0.f) * dg;
        o.z = fmaxf(o.z, 0.f) * dg; o.w = fmaxf(o.w, 0.f) * dg;
    }
    *(float4*)&out[(size_t)g * FEAT + f] = o;
}

extern "C" void kernel_launch(void* const* d_in, const int* in_sizes, int n_in,
                              void* d_out, int out_size, void* d_ws, size_t ws_size,
                              hipStream_t stream) {
    const float* x  = (const float*)d_in[0];
    const int*   ei = (const int*)d_in[1];
    const float* W0 = (const float*)d_in[2];
    const float* b0 = (const float*)d_in[3];
    const float* W1 = (const float*)d_in[4];
    const float* b1 = (const float*)d_in[5];
    const float* W2 = (const float*)d_in[6];
    const float* b2 = (const float*)d_in[7];
    float* out = (float*)d_out;

    const int N = in_sizes[0] / FEAT;   // 50000
    const int E = in_sizes[1] / 2;      // 800000 (divisible by 4)
    const int* src = ei;
    const int* dst = ei + E;

    const int nbScan = (N + SCAN_B - 1) / SCAN_B;   // 49

    // workspace layout
    char* w = (char*)d_ws;
    int*   cnt    = (int*)w;                 w += sizeof(int) * (size_t)N;
    int*   rowptr = (int*)w;                 w += sizeof(int) * (size_t)(N + 1);
    int*   bsum   = (int*)w;                 w += sizeof(int) * (size_t)(nbScan + 1);
    int*   col    = (int*)w;                 w += sizeof(int) * (size_t)E;
    float* dinv   = (float*)w;               w += sizeof(float) * (size_t)N;
    float* B1     = (float*)w;               w += sizeof(float) * (size_t)N * FEAT;
    float* B2     = (float*)w;               w += sizeof(float) * (size_t)N * FEAT;
    int*   rank   = (int*)B2;   // alias: rank dead before layer0 writes B2

    const int tB = 256;
    const int E4  = E / 4;
    const int gE4 = (E4 + tB - 1) / tB;
    const int g16 = (N + 15) / 16;

    // CSR build (shared by all 3 layers)
    hipMemsetAsync(cnt, 0, sizeof(int) * (size_t)N, stream);
    deg_rank_kernel<<<gE4, tB, 0, stream>>>(dst, cnt, rank, E4);
    scan_partial_kernel<<<nbScan, SCAN_B, 0, stream>>>(cnt, rowptr, bsum, dinv, N);
    scan_sums_kernel<<<1, SCAN_B, 0, stream>>>(bsum, nbScan);
    scan_add_kernel<<<nbScan, SCAN_B, 0, stream>>>(rowptr, bsum, N, nbScan);
    fill_kernel<<<gE4, tB, 0, stream>>>(src, dst, rank, rowptr, col, E4);

    // fused layers (layer 0 prescales its gather on the fly)
    layer_kernel<1, 1><<<g16, tB, 0, stream>>>(rowptr, col, dinv, x,  W0, b0, B2, N);
    layer_kernel<1, 0><<<g16, tB, 0, stream>>>(rowptr, col, dinv, B2, W1, b1, B1, N);
    layer_kernel<0, 0><<<g16, tB, 0, stream>>>(rowptr, col, dinv, B1, W2, b2, out, N);
}